// Round 7
// baseline (476.051 us; speedup 1.0000x reference)
//
#include <hip/hip_runtime.h>

typedef unsigned short u16;
typedef __attribute__((ext_vector_type(8))) _Float16 f16x8;
typedef __attribute__((ext_vector_type(16))) float f32x16;

#define N_SP 4096
#define C_CH 512
#define B_SZ 4

struct PtrTab { u16* p[4]; };

__device__ __forceinline__ u16 f2h(float f) {
    union { _Float16 h; u16 u; } x; x.h = (_Float16)f; return x.u;
}
__device__ __forceinline__ float h2f(u16 u) {
    union { u16 u; _Float16 h; } x; x.u = u; return (float)x.h;
}
__device__ __forceinline__ void async_cp16(const void* g, void* l) {
    __builtin_amdgcn_global_load_lds((const __attribute__((address_space(1))) unsigned*)g,
                                     (__attribute__((address_space(3))) unsigned*)l, 16, 0, 0);
}
__device__ __forceinline__ float wave_reduce_sum(float v) {
    #pragma unroll
    for (int off = 32; off; off >>= 1) v += __shfl_xor(v, off, 64);
    return v;
}

// ---- transpose+cast raw x to fp16 [b][n][c], accumulate per-channel partial stats ----
__global__ __launch_bounds__(256) void transpose_cast_stats(
        const float* __restrict__ fc, const float* __restrict__ fs,
        u16* __restrict__ xc, u16* __restrict__ xs,
        float* __restrict__ part_s, float* __restrict__ part_ss) {
    __shared__ float tile[64][65];
    const int t = threadIdx.x;
    const int n0 = blockIdx.x * 64, c0 = blockIdx.y * 64;
    const int z = blockIdx.z;                      // (which<<2)|b
    const int b = z & 3, which = z >> 2;
    const float* src = which ? fs : fc;
    u16* dst = which ? xs : xc;
    const int r = t >> 4, q4 = (t & 15) * 4;
    #pragma unroll
    for (int it = 0; it < 4; ++it) {
        const int row = it * 16 + r;
        float4 v = *(const float4*)(src + ((size_t)b * C_CH + c0 + row) * N_SP + n0 + q4);
        tile[row][q4 + 0] = v.x; tile[row][q4 + 1] = v.y;
        tile[row][q4 + 2] = v.z; tile[row][q4 + 3] = v.w;
    }
    __syncthreads();
    {
        const int cr = t >> 2, q = t & 3;
        float s = 0.f, ss = 0.f;
        #pragma unroll
        for (int i = 0; i < 16; ++i) {
            float a = tile[cr][q * 16 + i];
            s += a; ss += a * a;
        }
        s += __shfl_xor(s, 1, 64);  s += __shfl_xor(s, 2, 64);
        ss += __shfl_xor(ss, 1, 64); ss += __shfl_xor(ss, 2, 64);
        if (q == 0) {
            atomicAdd(&part_s[z * 512 + c0 + cr], s);
            atomicAdd(&part_ss[z * 512 + c0 + cr], ss);
        }
    }
    #pragma unroll
    for (int it = 0; it < 4; ++it) {
        const int nrow = it * 16 + r;
        ushort4 h4;
        h4.x = f2h(tile[q4 + 0][nrow]);
        h4.y = f2h(tile[q4 + 1][nrow]);
        h4.z = f2h(tile[q4 + 2][nrow]);
        h4.w = f2h(tile[q4 + 3][nrow]);
        *(ushort4*)(dst + ((size_t)b * N_SP + n0 + nrow) * C_CH + c0 + q4) = h4;
    }
}

// ---- prep1: weight transpose/cast + finalize stats + wu gemv + bfold gemv ----
// Wbase slots (each 262144 u16): 0 Ws1T, 1 Wcs16, 2 Wc1T, 3 Ws2T, 4 WqT16, 5 Wf16
__global__ __launch_bounds__(256) void prep1(
        const float* __restrict__ W_c1, const float* __restrict__ W_s1,
        const float* __restrict__ W_s2, const float* __restrict__ W_csc,
        const float* __restrict__ b_c1, const float* __restrict__ b_s2,
        const float* __restrict__ b_csc,
        u16* __restrict__ Wbase,
        const float* __restrict__ part_s, const float* __restrict__ part_ss,
        float* __restrict__ mu_a, float* __restrict__ rs_a,
        float* __restrict__ w_u, float* __restrict__ bfold0) {
    __shared__ float tile[64][65];
    const int t = threadIdx.x, z = blockIdx.z;
    if (z < 4) {
        const int n0 = blockIdx.x * 64, c0 = blockIdx.y * 64;
        const float* W = (z == 0) ? W_c1 : (z == 1) ? W_s1 : (z == 2) ? W_s2 : W_csc;
        u16* D = Wbase + ((z == 0) ? 2 : (z == 1) ? 0 : (z == 2) ? 3 : 1) * 262144;
        const int r = t >> 4, q4 = (t & 15) * 4;
        #pragma unroll
        for (int it = 0; it < 4; ++it) {
            const int row = it * 16 + r;
            float4 v = *(const float4*)(W + (size_t)(c0 + row) * 512 + n0 + q4);
            if (z == 3) {
                ushort4 h4 = { f2h(v.x), f2h(v.y), f2h(v.z), f2h(v.w) };
                *(ushort4*)(D + (size_t)(c0 + row) * 512 + n0 + q4) = h4;
            } else {
                tile[row][q4 + 0] = v.x; tile[row][q4 + 1] = v.y;
                tile[row][q4 + 2] = v.z; tile[row][q4 + 3] = v.w;
            }
        }
        __syncthreads();
        if (z == 3) return;
        #pragma unroll
        for (int it = 0; it < 4; ++it) {
            const int nrow = it * 16 + r;
            ushort4 h4;
            h4.x = f2h(tile[q4 + 0][nrow]);
            h4.y = f2h(tile[q4 + 1][nrow]);
            h4.z = f2h(tile[q4 + 2][nrow]);
            h4.w = f2h(tile[q4 + 3][nrow]);
            *(ushort4*)(D + (size_t)(n0 + nrow) * 512 + c0 + q4) = h4;
        }
        return;
    }
    const int flat = blockIdx.y * 8 + blockIdx.x;
    if (flat < 8) {               // finalize stats
        #pragma unroll
        for (int h = 0; h < 2; ++h) {
            const int c = flat * 512 + h * 256 + t;
            const float S = part_s[c], SS = part_ss[c];
            const float mean = S * (1.f / N_SP);
            const float var = (SS - S * mean) * (1.f / (N_SP - 1));
            mu_a[c] = mean;
            rs_a[c] = rsqrtf(var + 1e-5f);
        }
    } else if (flat < 10) {       // w_u[d] = sum_o b_c1[o] W_s1[o][d]
        const int d = (flat - 8) * 256 + t;
        float acc = 0.f;
        for (int o = 0; o < 512; ++o) acc += b_c1[o] * W_s1[(size_t)o * 512 + d];
        w_u[d] = acc;
    } else if (flat < 42) {       // bfold0[o] = sum_c W_csc[o][c] b_s2[c] + b_csc[o]
        const int w4 = t >> 6, l = t & 63;
        #pragma unroll
        for (int q = 0; q < 4; ++q) {
            const int o = (flat - 10) * 16 + w4 * 4 + q;
            const float4 w0 = *(const float4*)(W_csc + (size_t)o * 512 + l * 8);
            const float4 w1 = *(const float4*)(W_csc + (size_t)o * 512 + l * 8 + 4);
            const float4 b0 = *(const float4*)(b_s2 + l * 8);
            const float4 b1 = *(const float4*)(b_s2 + l * 8 + 4);
            float acc = w0.x * b0.x + w0.y * b0.y + w0.z * b0.z + w0.w * b0.w
                      + w1.x * b1.x + w1.y * b1.y + w1.z * b1.z + w1.w * b1.w;
            acc = wave_reduce_sum(acc);
            if (l == 0) bfold0[o] = acc + b_csc[o];
        }
    }
}

// ---- prep2: make_scaled + bias2 + u_big, one launch ----
__global__ __launch_bounds__(256) void prep2(
        const u16* __restrict__ WqT16, const u16* __restrict__ Wf16,
        const u16* __restrict__ xs,
        const float* __restrict__ mu_a, const float* __restrict__ rs_a,
        const float* __restrict__ bfold0, const float* __restrict__ w_u,
        u16* __restrict__ Wq_z, u16* __restrict__ Wf_z,
        float* __restrict__ bq, float* __restrict__ bh, float* __restrict__ u_) {
    const int id = blockIdx.x, t = threadIdx.x;
    if (id < 1024) {              // make_scaled
        const int y = id >> 9;
        const size_t e = ((size_t)(id & 511) * 256 + t) * 8;
        const int z = (int)(e >> 18), rem = (int)(e & 262143);
        const int d = rem >> 9, a0 = rem & 511;
        u16 v[8];
        if (y == 0) {
            *(uint4*)v = *(const uint4*)(WqT16 + rem);
            const float rd = rs_a[(4 + z) * 512 + d];
            const float* rc = rs_a + z * 512 + a0;
            #pragma unroll
            for (int i = 0; i < 8; ++i) v[i] = f2h(h2f(v[i]) * rc[i] * rd);
            *(uint4*)(Wq_z + e) = *(const uint4*)v;
        } else {
            *(uint4*)v = *(const uint4*)(Wf16 + rem);
            const float* rk = rs_a + (4 + z) * 512 + a0;
            #pragma unroll
            for (int i = 0; i < 8; ++i) v[i] = f2h(h2f(v[i]) * rk[i]);
            *(uint4*)(Wf_z + e) = *(const uint4*)v;
        }
    } else if (id < 2048) {       // bias2
        const int w = t >> 6, l = t & 63;
        const int oid = (id - 1024) * 4 + w;
        const int kind = oid >> 11;
        const int z = (oid >> 9) & 3, d = oid & 511;
        const u16* row = (kind == 0 ? WqT16 : Wf16) + (size_t)d * 512;
        const int sb = (kind == 0 ? z : 4 + z) * 512;
        float acc = 0.f;
        #pragma unroll
        for (int i = 0; i < 8; ++i) {
            const int a = l * 8 + i;
            acc += h2f(row[a]) * mu_a[sb + a] * rs_a[sb + a];
        }
        acc = wave_reduce_sum(acc);
        if (l == 0) {
            if (kind == 0) bq[z * 512 + d] = -acc * rs_a[(4 + z) * 512 + d];
            else           bh[z * 512 + d] = bfold0[d] - acc;
        }
    } else {                      // u_big
        const int id2 = id - 2048;                 // 0..255
        const int b = id2 >> 6, xblk = id2 & 63;
        const int w = t >> 6, l = t & 63;
        float4 u0 = *(const float4*)(w_u + l * 8);
        float4 u1 = *(const float4*)(w_u + l * 8 + 4);
        const float4 r0 = *(const float4*)(rs_a + (4 + b) * 512 + l * 8);
        const float4 r1 = *(const float4*)(rs_a + (4 + b) * 512 + l * 8 + 4);
        u0.x *= r0.x; u0.y *= r0.y; u0.z *= r0.z; u0.w *= r0.w;
        u1.x *= r1.x; u1.y *= r1.y; u1.z *= r1.z; u1.w *= r1.w;
        #pragma unroll
        for (int jj = 0; jj < 16; ++jj) {
            const int j = xblk * 64 + w * 16 + jj;
            const u16* row = xs + ((size_t)b * N_SP + j) * C_CH + l * 8;
            f16x8 x = *(const f16x8*)row;
            float acc = (float)x[0] * u0.x + (float)x[1] * u0.y + (float)x[2] * u0.z + (float)x[3] * u0.w
                      + (float)x[4] * u1.x + (float)x[5] * u1.y + (float)x[6] * u1.z + (float)x[7] * u1.w;
            acc = wave_reduce_sum(acc);
            if (l == 0) u_[(size_t)b * N_SP + j] = acc;
        }
    }
}

// ---------------- generic fp16 GEMM (convs + weight GEMM), 32x32x16, BK=64, XOR swizzle ----------------
__global__ __launch_bounds__(256) void gemm_conv(
    const u16* __restrict__ A, const u16* __restrict__ B, u16* __restrict__ Dh,
    const float* __restrict__ bias_m, const float* __restrict__ bias_n,
    int lda, int ldb, int ldd,
    size_t sA, size_t sB, size_t sD, int sBm, int sBn, int K)
{
    constexpr int TM = 128, TN = 128, BK = 64;
    __shared__ u16 smem[(TM + TN) * BK];
    u16* As = smem;
    u16* Bs = smem + TM * BK;

    const int t = threadIdx.x;
    const int l = t & 63, w = t >> 6;
    const int m0 = blockIdx.y * TM, n0 = blockIdx.x * TN;
    const size_t zb = blockIdx.z;
    const u16* pA = A + zb * sA + (size_t)m0 * lda;
    const u16* pB = B + zb * sB + (size_t)n0 * ldb;
    const int wr = (w & 1) * 64, wc = (w >> 1) * 64;

    f32x16 acc[2][2] = {};

    for (int k0 = 0; k0 < K; k0 += BK) {
        #pragma unroll
        for (int it = 0; it < 4; ++it) {
            const int L = it * 256 + t;
            const int row = L >> 3, c = L & 7;
            const int sc = (c ^ (row & 7)) * 8;
            async_cp16(pA + (size_t)row * lda + k0 + sc, As + L * 8);
        }
        #pragma unroll
        for (int it = 0; it < 4; ++it) {
            const int L = it * 256 + t;
            const int row = L >> 3, c = L & 7;
            const int sc = (c ^ (row & 7)) * 8;
            async_cp16(pB + (size_t)row * ldb + k0 + sc, Bs + L * 8);
        }
        __syncthreads();
        #pragma unroll
        for (int kk = 0; kk < 4; ++kk) {
            f16x8 af[2], bf[2];
            #pragma unroll
            for (int i = 0; i < 2; ++i) {
                const int row = wr + i * 32 + (l & 31);
                const int ch = ((kk * 2 + (l >> 5)) ^ (row & 7)) * 8;
                af[i] = *(const f16x8*)(As + row * BK + ch);
            }
            #pragma unroll
            for (int j = 0; j < 2; ++j) {
                const int row = wc + j * 32 + (l & 31);
                const int ch = ((kk * 2 + (l >> 5)) ^ (row & 7)) * 8;
                bf[j] = *(const f16x8*)(Bs + row * BK + ch);
            }
            #pragma unroll
            for (int i = 0; i < 2; ++i)
                #pragma unroll
                for (int j = 0; j < 2; ++j)
                    acc[i][j] = __builtin_amdgcn_mfma_f32_32x32x16_f16(af[i], bf[j], acc[i][j], 0, 0, 0);
        }
        __syncthreads();
    }

    const int cl = l & 31, rh = (l >> 5) * 4;
    u16* pDh = Dh + zb * sD;
    #pragma unroll
    for (int i = 0; i < 2; ++i) {
        #pragma unroll
        for (int j = 0; j < 2; ++j) {
            const int nn = n0 + wc + j * 32 + cl;
            const float bn = bias_n ? bias_n[(size_t)sBn * zb + nn] : 0.f;
            #pragma unroll
            for (int reg = 0; reg < 16; ++reg) {
                const int ml = (reg & 3) + 8 * (reg >> 2) + rh;
                const int mm = m0 + wr + i * 32 + ml;
                float v = acc[i][j][reg] + bn;
                if (bias_m) v += bias_m[(size_t)sBm * zb + mm];
                pDh[(size_t)mm * ldd + nn] = f2h(v);
            }
        }
    }
}

// ---------------- scores GEMM with fused partial-softmax epilogue ----------------
// S[i][j] = sum_d q'[i][d] Xs[j][d] + u[j]; stores P = exp(S - m_blk) fp16,
// writes per-(row, jblk) partials m_blk, l_blk.
__global__ __launch_bounds__(256) void gemm_scores(
    const u16* __restrict__ A, const u16* __restrict__ B, PtrTab Stab,
    const float* __restrict__ u_,
    float* __restrict__ part_m, float* __restrict__ part_l)
{
    constexpr int TM = 128, TN = 128, BK = 64, K = C_CH;
    __shared__ u16 smem[(TM + TN) * BK];
    u16* As = smem;
    u16* Bs = smem + TM * BK;

    const int t = threadIdx.x;
    const int l = t & 63, w = t >> 6;
    const int m0 = blockIdx.y * TM, n0 = blockIdx.x * TN;
    const size_t zb = blockIdx.z;
    const u16* pA = A + zb * (size_t)(N_SP * C_CH) + (size_t)m0 * C_CH;
    const u16* pB = B + zb * (size_t)(N_SP * C_CH) + (size_t)n0 * C_CH;
    const int wr = (w & 1) * 64, wc = (w >> 1) * 64;

    f32x16 acc[2][2] = {};

    for (int k0 = 0; k0 < K; k0 += BK) {
        #pragma unroll
        for (int it = 0; it < 4; ++it) {
            const int L = it * 256 + t;
            const int row = L >> 3, c = L & 7;
            const int sc = (c ^ (row & 7)) * 8;
            async_cp16(pA + (size_t)row * C_CH + k0 + sc, As + L * 8);
        }
        #pragma unroll
        for (int it = 0; it < 4; ++it) {
            const int L = it * 256 + t;
            const int row = L >> 3, c = L & 7;
            const int sc = (c ^ (row & 7)) * 8;
            async_cp16(pB + (size_t)row * C_CH + k0 + sc, Bs + L * 8);
        }
        __syncthreads();
        #pragma unroll
        for (int kk = 0; kk < 4; ++kk) {
            f16x8 af[2], bf[2];
            #pragma unroll
            for (int i = 0; i < 2; ++i) {
                const int row = wr + i * 32 + (l & 31);
                const int ch = ((kk * 2 + (l >> 5)) ^ (row & 7)) * 8;
                af[i] = *(const f16x8*)(As + row * BK + ch);
            }
            #pragma unroll
            for (int j = 0; j < 2; ++j) {
                const int row = wc + j * 32 + (l & 31);
                const int ch = ((kk * 2 + (l >> 5)) ^ (row & 7)) * 8;
                bf[j] = *(const f16x8*)(Bs + row * BK + ch);
            }
            #pragma unroll
            for (int i = 0; i < 2; ++i)
                #pragma unroll
                for (int j = 0; j < 2; ++j)
                    acc[i][j] = __builtin_amdgcn_mfma_f32_32x32x16_f16(af[i], bf[j], acc[i][j], 0, 0, 0);
        }
        __syncthreads();
    }

    // ---- fused epilogue: row max / sum-exp partials + store P = exp(S - m_blk) ----
    const int cl = l & 31, h = l >> 5;
    const float uj0 = u_[zb * N_SP + n0 + wc + cl];
    const float uj1 = u_[zb * N_SP + n0 + wc + 32 + cl];
    float* red_m = (float*)smem;          // [128]
    float* red_l = red_m + 128;           // [128]

    // local (64-col) row max per (i, reg)
    float lm[2][16];
    #pragma unroll
    for (int i = 0; i < 2; ++i)
        #pragma unroll
        for (int r = 0; r < 16; ++r) {
            float a0 = acc[i][0][r] + uj0;
            float a1 = acc[i][1][r] + uj1;
            acc[i][0][r] = a0; acc[i][1][r] = a1;
            float m = fmaxf(a0, a1);
            #pragma unroll
            for (int off = 1; off <= 16; off <<= 1) m = fmaxf(m, __shfl_xor(m, off, 64));
            lm[i][r] = m;
        }
    // combine wave pairs (cols 0-63 with 64-127): w<2 writes, w>=2 maxes
    if (w < 2) {
        #pragma unroll
        for (int i = 0; i < 2; ++i)
            #pragma unroll
            for (int r = 0; r < 16; ++r)
                if (cl == 0) red_m[wr + i * 32 + (r & 3) + 8 * (r >> 2) + 4 * h] = lm[i][r];
    }
    __syncthreads();
    if (w >= 2) {
        #pragma unroll
        for (int i = 0; i < 2; ++i)
            #pragma unroll
            for (int r = 0; r < 16; ++r)
                if (cl == 0) {
                    const int rr = wr + i * 32 + (r & 3) + 8 * (r >> 2) + 4 * h;
                    red_m[rr] = fmaxf(red_m[rr], lm[i][r]);
                }
    }
    __syncthreads();
    // exps, store P, local sums
    u16* pP = Stab.p[zb];
    float ls[2][16];
    #pragma unroll
    for (int i = 0; i < 2; ++i)
        #pragma unroll
        for (int r = 0; r < 16; ++r) {
            const int rr = wr + i * 32 + (r & 3) + 8 * (r >> 2) + 4 * h;
            const float m = red_m[rr];
            const float e0 = __expf(acc[i][0][r] - m);
            const float e1 = __expf(acc[i][1][r] - m);
            const size_t rowbase = (size_t)(m0 + rr) * N_SP + n0 + wc;
            pP[rowbase + cl] = f2h(e0);
            pP[rowbase + 32 + cl] = f2h(e1);
            float s = e0 + e1;
            #pragma unroll
            for (int off = 1; off <= 16; off <<= 1) s += __shfl_xor(s, off, 64);
            ls[i][r] = s;
        }
    if (w < 2) {
        #pragma unroll
        for (int i = 0; i < 2; ++i)
            #pragma unroll
            for (int r = 0; r < 16; ++r)
                if (cl == 0) red_l[wr + i * 32 + (r & 3) + 8 * (r >> 2) + 4 * h] = ls[i][r];
    }
    __syncthreads();
    if (w >= 2) {
        #pragma unroll
        for (int i = 0; i < 2; ++i)
            #pragma unroll
            for (int r = 0; r < 16; ++r)
                if (cl == 0) {
                    const int rr = wr + i * 32 + (r & 3) + 8 * (r >> 2) + 4 * h;
                    const size_t base = ((size_t)zb * N_SP + m0 + rr) * 32 + blockIdx.x;
                    part_m[base] = red_m[rr];
                    part_l[base] = red_l[rr] + ls[i][r];
                }
    }
}

// ---- finalize softmax: per row m = max m_b, l = sum l_b exp(m_b-m); corr = exp(m_b-m)/l ----
__global__ __launch_bounds__(256) void reduce_corr(const float* __restrict__ part_m,
                                                   const float* __restrict__ part_l,
                                                   float* __restrict__ corr) {
    const int t = threadIdx.x;
    const int half = t >> 5, cl = t & 31;
    const size_t row = (size_t)blockIdx.x * 8 + half;       // 0..16383
    const float m = part_m[row * 32 + cl];
    const float lsum = part_l[row * 32 + cl];
    float mm = m;
    #pragma unroll
    for (int off = 1; off <= 16; off <<= 1) mm = fmaxf(mm, __shfl_xor(mm, off, 64));
    const float e = __expf(m - mm);
    float tot = lsum * e;
    #pragma unroll
    for (int off = 1; off <= 16; off <<= 1) tot += __shfl_xor(tot, off, 64);
    corr[row * 32 + cl] = e / tot;
}

// ---------------- PV GEMM: out[b][o][i] = sum_j hc[o][j] (P[i][j]*corr[i][jblk]) + f_c ----------------
__global__ __launch_bounds__(256) void gemm_pv(
    const u16* __restrict__ A /*hc*/, PtrTab Stab, const float* __restrict__ corr,
    float* __restrict__ out, const float* __restrict__ res)
{
    constexpr int TM = 128, TN = 128, BK = 64, K = N_SP;
    __shared__ u16 smem[(TM + TN) * BK];
    u16* As = smem;
    u16* Bs = smem + TM * BK;

    const int t = threadIdx.x;
    const int l = t & 63, w = t >> 6;
    const int m0 = blockIdx.y * TM, n0 = blockIdx.x * TN;
    const size_t zb = blockIdx.z;
    const size_t PB = (size_t)N_SP * C_CH;
    const u16* pA = A + zb * PB + (size_t)m0 * N_SP;
    const u16* pB = Stab.p[zb] + (size_t)n0 * N_SP;
    const float* pc = corr + ((size_t)zb * N_SP + n0) * 32;
    const int wr = (w & 1) * 64, wc = (w >> 1) * 64;

    f32x16 acc[2][2] = {};

    for (int k0 = 0; k0 < K; k0 += BK) {
        #pragma unroll
        for (int it = 0; it < 4; ++it) {
            const int L = it * 256 + t;
            const int row = L >> 3, c = L & 7;
            const int sc = (c ^ (row & 7)) * 8;
            async_cp16(pA + (size_t)row * N_SP + k0 + sc, As + L * 8);
        }
        const int jblk = k0 >> 7;
        #pragma unroll
        for (int it = 0; it < 4; ++it) {
            const int L = it * 256 + t;
            const int row = L >> 3, c = L & 7;
            const int sc = (c ^ (row & 7)) * 8;
            const float cr = pc[row * 32 + jblk];
            f16x8 x = *(const f16x8*)(pB + (size_t)row * N_SP + k0 + sc);
            f16x8 y;
            #pragma unroll
            for (int e = 0; e < 8; ++e) y[e] = (_Float16)((float)x[e] * cr);
            *(f16x8*)(Bs + (size_t)L * 8) = y;
        }
        __syncthreads();
        #pragma unroll
        for (int kk = 0; kk < 4; ++kk) {
            f16x8 af[2], bf[2];
            #pragma unroll
            for (int i = 0; i < 2; ++i) {
                const int row = wr + i * 32 + (l & 31);
                const int ch = ((kk * 2 + (l >> 5)) ^ (row & 7)) * 8;
                af[i] = *(const f16x8*)(As + row * BK + ch);
            }
            #pragma unroll
            for (int j = 0; j < 2; ++j) {
                const int row = wc + j * 32 + (l & 31);
                const int ch = ((kk * 2 + (l >> 5)) ^ (row & 7)) * 8;
                bf[j] = *(const f16x8*)(Bs + row * BK + ch);
            }
            #pragma unroll
            for (int i = 0; i < 2; ++i)
                #pragma unroll
                for (int j = 0; j < 2; ++j)
                    acc[i][j] = __builtin_amdgcn_mfma_f32_32x32x16_f16(af[i], bf[j], acc[i][j], 0, 0, 0);
        }
        __syncthreads();
    }

    const int cl = l & 31, rh = (l >> 5) * 4;
    float* pDf = out + zb * PB;
    const float* pR = res + zb * PB;
    #pragma unroll
    for (int i = 0; i < 2; ++i) {
        #pragma unroll
        for (int j = 0; j < 2; ++j) {
            const int nn = n0 + wc + j * 32 + cl;
            #pragma unroll
            for (int reg = 0; reg < 16; ++reg) {
                const int ml = (reg & 3) + 8 * (reg >> 2) + rh;
                const int mm = m0 + wr + i * 32 + ml;
                const size_t off = (size_t)mm * N_SP + nn;
                pDf[off] = acc[i][j][reg] + pR[off];
            }
        }
    }
}

extern "C" void kernel_launch(void* const* d_in, const int* in_sizes, int n_in,
                              void* d_out, int out_size, void* d_ws, size_t ws_size,
                              hipStream_t stream) {
    const float* f_c   = (const float*)d_in[0];
    const float* f_s   = (const float*)d_in[1];
    const float* W_c1  = (const float*)d_in[2];
    const float* b_c1  = (const float*)d_in[3];
    const float* W_s1  = (const float*)d_in[4];
    const float* b_s1  = (const float*)d_in[5]; (void)b_s1;   // softmax-invariant, dropped
    const float* W_s2  = (const float*)d_in[6];
    const float* b_s2  = (const float*)d_in[7];
    const float* W_csc = (const float*)d_in[8];
    const float* b_csc = (const float*)d_in[9];

    const size_t PB = (size_t)N_SP * C_CH;      // 2M elems per batch plane
    const size_t M1 = 1024 * 1024;

    u16* ws   = (u16*)d_ws;
    u16* Xs   = ws;                 // raw fp16 [b][j][c]   0..8M
    u16* q_   = ws + 8 * M1;        // q'[b][i][d]          8..16M
    u16* hc   = ws + 16 * M1;       // hc[b][o][j]          16..24M
    u16* Xc   = ws + 24 * M1;       // raw fp16 (dead after q'-conv; S3 aliases)
    u16* S3   = ws + 24 * M1;
    u16* S0   = ws + 40 * M1;
    u16* S1   = ws + 56 * M1;
    u16* S2   = ws + 72 * M1;
    u16* Wbase= ws + 88 * M1;       // 6 x 262144: Ws1T, Wcs16, Wc1T, Ws2T, WqT16, Wf16
    u16* WqT16= Wbase + 4 * 262144;
    u16* Wf16 = Wbase + 5 * 262144;
    u16* Wq_z = Wbase + 6 * 262144; // 4 x 256K
    u16* Wf_z = Wq_z + 1048576;     // 4 x 256K
    float* f32b = (float*)(ws + 92 * M1);
    float* part_s  = f32b;          // 4096
    float* part_ss = f32b + 4096;
    float* mu_a    = f32b + 8192;
    float* rs_a    = f32b + 12288;
    float* w_u     = f32b + 16384;  // 512
    float* bfold0  = f32b + 16896;  // 512
    float* bq      = f32b + 17408;  // 2048
    float* bh      = f32b + 19456;  // 2048
    float* u_      = f32b + 21504;  // 4*4096
    float* part_m  = f32b + 65536;  // 4*4096*32
    float* part_l  = part_m + 524288;
    float* corr    = part_l + 524288;

    PtrTab Stab; Stab.p[0] = S0; Stab.p[1] = S1; Stab.p[2] = S2; Stab.p[3] = S3;

    hipMemsetAsync(part_s, 0, 2 * 4096 * sizeof(float), stream);

    transpose_cast_stats<<<dim3(64, 8, 8), 256, 0, stream>>>(f_c, f_s, Xc, Xs, part_s, part_ss);

    prep1<<<dim3(8, 8, 5), 256, 0, stream>>>(W_c1, W_s1, W_s2, W_csc, b_c1, b_s2, b_csc,
                                             Wbase, part_s, part_ss, mu_a, rs_a, w_u, bfold0);

    // WqT[d][a] = sum_o Ws1T[d][o] Wc1T[a][o]; Wfold[o][k] = sum_c Wcs16[o][c] Ws2T[k][c]
    gemm_conv<<<dim3(4, 4, 2), 256, 0, stream>>>(
        Wbase, Wbase + 2 * 262144, WqT16, nullptr, nullptr,
        512, 512, 512, 262144, 262144, 262144, 0, 0, 512);

    prep2<<<2304, 256, 0, stream>>>(WqT16, Wf16, Xs, mu_a, rs_a, bfold0, w_u,
                                    Wq_z, Wf_z, bq, bh, u_);

    // q'[b][i][d] = sum_a Xc_raw[b][i][a] Wq_z[b][d][a] + bq[b][d]
    gemm_conv<<<dim3(4, 32, B_SZ), 256, 0, stream>>>(
        Xc, Wq_z, q_, nullptr, bq,
        C_CH, C_CH, C_CH, PB, 262144, PB, 0, 512, 512);
    // hc[b][o][j] = sum_k Wf_z[b][o][k] Xs_raw[b][j][k] + bh[b][o]
    gemm_conv<<<dim3(32, 4, B_SZ), 256, 0, stream>>>(
        Wf_z, Xs, hc, bh, nullptr,
        C_CH, C_CH, N_SP, 262144, PB, PB, 512, 0, 512);

    // scores + partial softmax, P = exp(S - m_blk) stored fp16
    gemm_scores<<<dim3(32, 32, B_SZ), 256, 0, stream>>>(q_, Xs, Stab, u_, part_m, part_l);

    reduce_corr<<<2048, 256, 0, stream>>>(part_m, part_l, corr);

    // PV with on-the-fly normalization + residual
    gemm_pv<<<dim3(32, 4, B_SZ), 256, 0, stream>>>(hc, Stab, corr, (float*)d_out, f_c);
}